// Round 6
// baseline (848.530 us; speedup 1.0000x reference)
//
#include <hip/hip_runtime.h>

#define NN 100000
#define NE 1600000
#define F  32
#define TILE  200        // nodes per tile; 500*200 == 100000 exactly
#define NTILE 500
#define CAP   7200       // entries per bucket; mean 6400, sigma ~78 -> +10 sigma
#define PADB  16         // bcur padding (one cache line per counter)

// ---- init: bucket cursors = 0, gsum = 0 (idempotent every call) ----
__global__ void k_init(int* __restrict__ bcur, float* __restrict__ gsum) {
    int i = blockIdx.x * blockDim.x + threadIdx.x;
    if (i < NTILE * PADB) bcur[i] = 0;
    if (i == 0) gsum[0] = 0.f;
}

// ---- bucket edges by target tile; entry = (node_local | dir<<8 | nbr<<9, w_bf16) ----
// dir 0: To-side (node=src, nbr=dst); dir 1: Ti-side (node=dst, nbr=src).
__global__ __launch_bounds__(1024) void k_bucket(const int* __restrict__ src,
                                                 const int* __restrict__ dst,
                                                 const float* __restrict__ ew,
                                                 int* __restrict__ bcur,
                                                 int* __restrict__ pool_i,
                                                 unsigned short* __restrict__ pool_w) {
    __shared__ int hcnt[NTILE], hbase[NTILE], hcur[NTILE];
    int t = threadIdx.x;
    for (int b = t; b < NTILE; b += 1024) { hcnt[b] = 0; hcur[b] = 0; }
    __syncthreads();
    int stride = gridDim.x * 1024;
    // round A: count per-block contributions per bucket
    for (int e = blockIdx.x * 1024 + t; e < NE; e += stride) {
        unsigned s = (unsigned)src[e], d = (unsigned)dst[e];
        atomicAdd(&hcnt[s / TILE], 1);
        atomicAdd(&hcnt[d / TILE], 1);
    }
    __syncthreads();
    // reserve global ranges (one atomic per bucket per block)
    for (int b = t; b < NTILE; b += 1024)
        hbase[b] = (hcnt[b] > 0) ? atomicAdd(&bcur[b * PADB], hcnt[b]) : 0;
    __syncthreads();
    // round B: place entries
    for (int e = blockIdx.x * 1024 + t; e < NE; e += stride) {
        unsigned s = (unsigned)src[e], d = (unsigned)dst[e];
        float w = ew[e];
        unsigned u = __float_as_uint(w) + 0x8000u;            // round-to-nearest bf16 (w>0)
        unsigned short wh = (unsigned short)(u >> 16);
        unsigned ts = s / TILE;
        int r = atomicAdd(&hcur[ts], 1);
        int pos = hbase[ts] + r;
        if (pos < CAP) {
            pool_i[ts * CAP + pos] = (int)((s - ts * TILE) | (0u << 8) | (d << 9));
            pool_w[ts * CAP + pos] = wh;
        }
        unsigned td = d / TILE;
        r = atomicAdd(&hcur[td], 1);
        pos = hbase[td] + r;
        if (pos < CAP) {
            pool_i[td * CAP + pos] = (int)((d - td * TILE) | (1u << 8) | (s << 9));
            pool_w[td * CAP + pos] = wh;
        }
    }
}

// ---- scatter: one block per tile; To/Ti accumulated in LDS, written back dense ----
__global__ __launch_bounds__(512) void k_scatter(const float* __restrict__ x,
                                                 const int* __restrict__ bcur,
                                                 const int* __restrict__ pool_i,
                                                 const unsigned short* __restrict__ pool_w,
                                                 float* __restrict__ To,
                                                 float* __restrict__ Ti,
                                                 float* __restrict__ deg_o,
                                                 float* __restrict__ deg_i) {
    __shared__ float acc[TILE * 66];   // [node][dir*33 + f]; stride 66 breaks bank alias
    __shared__ float dacc[TILE * 2];
    int tile = blockIdx.x;
    int t = threadIdx.x;
    for (int idx = t; idx < TILE * 66; idx += 512) acc[idx] = 0.f;
    for (int idx = t; idx < TILE * 2;  idx += 512) dacc[idx] = 0.f;
    __syncthreads();

    int cnt = bcur[tile * PADB];
    if (cnt > CAP) cnt = CAP;
    int f  = t & 31;
    int hw = t >> 5;                   // 16 half-waves
    const int base = tile * CAP;
    for (int j = hw; j < cnt; j += 16) {
        int pi = pool_i[base + j];
        float w = __uint_as_float(((unsigned)pool_w[base + j]) << 16);
        int nl  = pi & 255;
        int dir = (pi >> 8) & 1;
        int nbr = ((unsigned)pi) >> 9;
        float v = w * x[(size_t)nbr * F + f];
        atomicAdd(&acc[nl * 66 + dir * 33 + f], v);
        if (f == 0) atomicAdd(&dacc[nl * 2 + dir], w);
    }
    __syncthreads();

    int nb = tile * TILE;
    for (int idx = t; idx < TILE * F; idx += 512) {
        int nl = idx >> 5, ff = idx & 31;
        To[(size_t)(nb + nl) * F + ff] = acc[nl * 66 + ff];
        Ti[(size_t)(nb + nl) * F + ff] = acc[nl * 66 + 33 + ff];
    }
    for (int idx = t; idx < TILE; idx += 512) {
        deg_o[nb + idx] = dacc[idx * 2];
        deg_i[nb + idx] = dacc[idx * 2 + 1];
    }
}

// ---- gates: thread per node, weights broadcast from LDS (verified math) ----
// gz = x@(Wz00+Wz10) + (To/deg_o)@Wz01 + (Ti/deg_i)@Wz11 + bz ; gh likewise with Wh.
// H = (1-sigmoid(gz))*tanh(gh); s = relu(H).Wlin summed into gsum.
__global__ __launch_bounds__(256) void RecurrentGCN_69587060130083_kernel(
    const float* __restrict__ x,
    const float* __restrict__ To, const float* __restrict__ Ti,
    const float* __restrict__ deg_o, const float* __restrict__ deg_i,
    const float* __restrict__ Wz, const float* __restrict__ bz,
    const float* __restrict__ Wh, const float* __restrict__ bh,
    const float* __restrict__ Wl,
    float* __restrict__ gsum)
{
    __shared__ float sWz0[1024], sWzo[1024], sWzi[1024];
    __shared__ float sWh0[1024], sWho[1024], sWhi[1024];
    __shared__ float sbz[32], sbh[32], swl[32];
    __shared__ float wsum[4];
    int tid = threadIdx.x;

    for (int idx = tid; idx < 1024; idx += 256) {
        int c = idx >> 5, f = idx & 31;
        int tr = f * 32 + c;
        // W[dir,k,c,f] flat = dir*4096 + k*2048 + c*32 + f ; only c<32 matters (H=0)
        sWz0[tr] = Wz[idx] + Wz[4096 + idx];
        sWzo[tr] = Wz[2048 + idx];
        sWzi[tr] = Wz[6144 + idx];
        sWh0[tr] = Wh[idx] + Wh[4096 + idx];
        sWho[tr] = Wh[2048 + idx];
        sWhi[tr] = Wh[6144 + idx];
    }
    if (tid < 32) {
        sbz[tid] = bz[tid];
        sbh[tid] = bh[tid];
        swl[tid] = Wl[tid];
    }
    __syncthreads();

    int i = blockIdx.x * 256 + tid;
    float s_acc = 0.f;
    if (i < NN) {
        float xv[F], tov[F], tiv[F];
        float dio = 1.f / deg_o[i], dii = 1.f / deg_i[i];
        const float4* xr  = (const float4*)(x  + (size_t)i * F);
        const float4* tor = (const float4*)(To + (size_t)i * F);
        const float4* tir = (const float4*)(Ti + (size_t)i * F);
#pragma unroll
        for (int j = 0; j < 8; j++) {
            float4 p = xr[j];
            xv[4*j+0] = p.x; xv[4*j+1] = p.y; xv[4*j+2] = p.z; xv[4*j+3] = p.w;
            float4 a = tor[j];
            tov[4*j+0] = a.x * dio; tov[4*j+1] = a.y * dio;
            tov[4*j+2] = a.z * dio; tov[4*j+3] = a.w * dio;
            float4 b = tir[j];
            tiv[4*j+0] = b.x * dii; tiv[4*j+1] = b.y * dii;
            tiv[4*j+2] = b.z * dii; tiv[4*j+3] = b.w * dii;
        }
#pragma unroll 4
        for (int f = 0; f < 32; f++) {
            float gz = sbz[f], gh = sbh[f];
            const float* wz0 = &sWz0[f * 32];
            const float* wzo = &sWzo[f * 32];
            const float* wzi = &sWzi[f * 32];
            const float* wh0 = &sWh0[f * 32];
            const float* who = &sWho[f * 32];
            const float* whi = &sWhi[f * 32];
#pragma unroll
            for (int c = 0; c < 32; c++) {
                gz += xv[c] * wz0[c] + tov[c] * wzo[c] + tiv[c] * wzi[c];
                gh += xv[c] * wh0[c] + tov[c] * who[c] + tiv[c] * whi[c];
            }
            float Z  = 1.f / (1.f + __expf(-gz));
            float Ht = tanhf(gh);
            float hv = (1.f - Z) * Ht;
            hv = hv > 0.f ? hv : 0.f;
            s_acc += hv * swl[f];
        }
    }
#pragma unroll
    for (int off = 32; off > 0; off >>= 1) s_acc += __shfl_down(s_acc, off);
    if ((tid & 63) == 0) wsum[tid >> 6] = s_acc;
    __syncthreads();
    if (tid == 0) atomicAdd(gsum, wsum[0] + wsum[1] + wsum[2] + wsum[3]);
}

__global__ void k_final(const float* __restrict__ gsum,
                        const float* __restrict__ blin,
                        float* __restrict__ out) {
    out[0] = gsum[0] / (float)NN + blin[0];
}

extern "C" void kernel_launch(void* const* d_in, const int* in_sizes, int n_in,
                              void* d_out, int out_size, void* d_ws, size_t ws_size,
                              hipStream_t stream) {
    const float* x  = (const float*)d_in[0];
    const float* ew = (const float*)d_in[1];
    const float* Wz = (const float*)d_in[2];
    const float* bz = (const float*)d_in[3];
    // d_in[4], d_in[5] = W_r, b_r: dead (H=0 => H*R=0)
    const float* Wh = (const float*)d_in[6];
    const float* bh = (const float*)d_in[7];
    const float* Wl = (const float*)d_in[8];
    const float* bl = (const float*)d_in[9];
    const int* ei  = (const int*)d_in[10];
    const int* src = ei;
    const int* dst = ei + NE;

    // ws layout (bytes): bcur 32KB | pool_i 14.4MB | pool_w 7.2MB | To 12.8MB |
    // Ti 12.8MB | deg_o 0.4MB | deg_i 0.4MB | gsum   (total ~48.0MB)
    int* iws = (int*)d_ws;
    int* bcur = iws;
    int* pool_i = bcur + NTILE * PADB;
    unsigned short* pool_w = (unsigned short*)(pool_i + (size_t)NTILE * CAP);
    float* To    = (float*)(pool_w + (size_t)NTILE * CAP);
    float* Ti    = To + (size_t)NN * F;
    float* deg_o = Ti + (size_t)NN * F;
    float* deg_i = deg_o + NN;
    float* gsum  = deg_i + NN;

    k_init  <<<(NTILE * PADB + 255) / 256, 256, 0, stream>>>(bcur, gsum);
    k_bucket<<<256, 1024, 0, stream>>>(src, dst, ew, bcur, pool_i, pool_w);
    k_scatter<<<NTILE, 512, 0, stream>>>(x, bcur, pool_i, pool_w, To, Ti, deg_o, deg_i);
    RecurrentGCN_69587060130083_kernel<<<(NN + 255) / 256, 256, 0, stream>>>(
        x, To, Ti, deg_o, deg_i, Wz, bz, Wh, bh, Wl, gsum);
    k_final<<<1, 1, 0, stream>>>(gsum, bl, (float*)d_out);
}

// Round 7
// 543.641 us; speedup vs baseline: 1.5608x; 1.5608x over previous
//
#include <hip/hip_runtime.h>

#define NN 100000
#define NE 1600000
#define F  32
#define TWO_N (2 * NN)
#define SCAN_BLOCKS 196   // ceil(200000 / 1024)
#define PS 2              // cursor pad stride (ints)
#define PART_N 12500      // nodes per XCD partition (NN/8)
#define PART_GRID 2048    // 8 partitions x 256 block-groups

// ---- init: padded count/cursor array = 0, gsum = 0 (idempotent every call) ----
__global__ void k_init(int* __restrict__ cur, float* __restrict__ gsum) {
    int i = blockIdx.x * blockDim.x + threadIdx.x;
    if (i < TWO_N * PS) cur[i] = 0;
    if (i == 0) gsum[0] = 0.f;
}

// ---- degree counts, XCD-partitioned; nt loads keep cursor lines L2-resident ----
__global__ __launch_bounds__(256) void k_count(const int* __restrict__ src,
                                               const int* __restrict__ dst,
                                               int* __restrict__ cur) {
    int part = blockIdx.x & 7;
    int grp  = blockIdx.x >> 3;
    int ngrp = gridDim.x >> 3;
    int lo = part * PART_N, hi = lo + PART_N;
    for (int e = grp * 256 + threadIdx.x; e < NE; e += ngrp * 256) {
        int s = __builtin_nontemporal_load(&src[e]);
        int d = __builtin_nontemporal_load(&dst[e]);
        if (s >= lo && s < hi) atomicAdd(&cur[(size_t)s * PS], 1);
        if (d >= lo && d < hi) atomicAdd(&cur[(size_t)(NN + d) * PS], 1);
    }
}

// ---- scan stage 1: per-block (1024 elems) exclusive scan + block sums ----
__global__ __launch_bounds__(256) void k_scanb(const int* __restrict__ cur,
                                               int* __restrict__ off,
                                               int* __restrict__ bsum) {
    __shared__ int s[256];
    int t = threadIdx.x, b = blockIdx.x;
    int base = b * 1024 + t * 4;
    int v0 = (base + 0 < TWO_N) ? cur[(size_t)(base + 0) * PS] : 0;
    int v1 = (base + 1 < TWO_N) ? cur[(size_t)(base + 1) * PS] : 0;
    int v2 = (base + 2 < TWO_N) ? cur[(size_t)(base + 2) * PS] : 0;
    int v3 = (base + 3 < TWO_N) ? cur[(size_t)(base + 3) * PS] : 0;
    int lsum = v0 + v1 + v2 + v3;
    s[t] = lsum;
    __syncthreads();
    for (int d = 1; d < 256; d <<= 1) {
        int add = (t >= d) ? s[t - d] : 0;
        __syncthreads();
        s[t] += add;
        __syncthreads();
    }
    int excl = s[t] - lsum;
    if (base + 0 < TWO_N) off[base + 0] = excl;            excl += v0;
    if (base + 1 < TWO_N) off[base + 1] = excl;            excl += v1;
    if (base + 2 < TWO_N) off[base + 2] = excl;            excl += v2;
    if (base + 3 < TWO_N) off[base + 3] = excl;
    if (t == 255) bsum[b] = s[255];
}

// ---- scan stage 2: exclusive scan of block sums (single block) ----
__global__ __launch_bounds__(256) void k_scant(const int* __restrict__ bsum,
                                               int* __restrict__ bbase) {
    __shared__ int s[256];
    int t = threadIdx.x;
    int v = (t < SCAN_BLOCKS) ? bsum[t] : 0;
    s[t] = v;
    __syncthreads();
    for (int d = 1; d < 256; d <<= 1) {
        int add = (t >= d) ? s[t - d] : 0;
        __syncthreads();
        s[t] += add;
        __syncthreads();
    }
    bbase[t] = s[t] - v;
}

// ---- scan stage 3: off = global exclusive prefix; cursor array <- starts ----
__global__ void k_scana(int* __restrict__ off, const int* __restrict__ bbase,
                        int* __restrict__ cur) {
    int i = blockIdx.x * blockDim.x + threadIdx.x;
    if (i < TWO_N) {
        int v = off[i] + bbase[i >> 10];
        off[i] = v;
        cur[(size_t)i * PS] = v;
    }
    if (i == 0) off[TWO_N] = 2 * NE;
}

// ---- fill CSR pool, XCD-partitioned; nt edge loads -> pool lines stay in L2 ----
__global__ __launch_bounds__(256) void k_fill(const int* __restrict__ src,
                                              const int* __restrict__ dst,
                                              const float* __restrict__ ew,
                                              int* __restrict__ cur,
                                              int2* __restrict__ pool) {
    int part = blockIdx.x & 7;
    int grp  = blockIdx.x >> 3;
    int ngrp = gridDim.x >> 3;
    int lo = part * PART_N, hi = lo + PART_N;
    for (int e = grp * 256 + threadIdx.x; e < NE; e += ngrp * 256) {
        int s = __builtin_nontemporal_load(&src[e]);
        int d = __builtin_nontemporal_load(&dst[e]);
        bool ws_ = (s >= lo && s < hi);
        bool wd_ = (d >= lo && d < hi);
        if (ws_ || wd_) {
            float w = __builtin_nontemporal_load(&ew[e]);
            if (ws_) {
                int p = atomicAdd(&cur[(size_t)s * PS], 1);
                pool[p] = make_int2(d, __float_as_int(w));
            }
            if (wd_) {
                int p = atomicAdd(&cur[(size_t)(NN + d) * PS], 1);
                pool[p] = make_int2(s, __float_as_int(w));
            }
        }
    }
}

// ---- gather: half-wave (32 lanes = 32 features) per node; 4x unrolled MLP ----
__device__ __forceinline__ int2 nt_pool(const int2* pool, int j) {
    const long long* pl = (const long long*)pool;
    long long v = __builtin_nontemporal_load(&pl[j]);
    int2 r; r.x = (int)(v & 0xffffffffLL); r.y = (int)(v >> 32);
    return r;
}

__global__ __launch_bounds__(256) void k_gather(const float* __restrict__ x,
                                                const int* __restrict__ off,
                                                const int2* __restrict__ pool,
                                                float* __restrict__ To,
                                                float* __restrict__ Ti) {
    int tid = threadIdx.x;
    int f = tid & 31;
    int i = blockIdx.x * 8 + (tid >> 5);
    if (i >= NN) return;

#pragma unroll
    for (int dir = 0; dir < 2; dir++) {
        int j0 = off[dir * NN + i], j1 = off[dir * NN + i + 1];
        float acc = 0.f, deg = 0.f;
        int j = j0;
        for (; j + 4 <= j1; j += 4) {
            int2 p0 = nt_pool(pool, j);
            int2 p1 = nt_pool(pool, j + 1);
            int2 p2 = nt_pool(pool, j + 2);
            int2 p3 = nt_pool(pool, j + 3);
            float x0 = x[(size_t)p0.x * F + f];
            float x1 = x[(size_t)p1.x * F + f];
            float x2 = x[(size_t)p2.x * F + f];
            float x3 = x[(size_t)p3.x * F + f];
            float w0 = __int_as_float(p0.y), w1 = __int_as_float(p1.y);
            float w2 = __int_as_float(p2.y), w3 = __int_as_float(p3.y);
            deg += (w0 + w1) + (w2 + w3);
            acc += w0 * x0 + w1 * x1 + w2 * x2 + w3 * x3;
        }
        for (; j < j1; j++) {
            int2 p = nt_pool(pool, j);
            float w = __int_as_float(p.y);
            deg += w;
            acc += w * x[(size_t)p.x * F + f];
        }
        float* dstp = dir ? Ti : To;
        dstp[(size_t)i * F + f] = acc / deg;
    }
}

// ---- gates: thread per node, weights broadcast from LDS (verified math) ----
__global__ __launch_bounds__(256) void RecurrentGCN_69587060130083_kernel(
    const float* __restrict__ x,
    const float* __restrict__ To, const float* __restrict__ Ti,
    const float* __restrict__ Wz, const float* __restrict__ bz,
    const float* __restrict__ Wh, const float* __restrict__ bh,
    const float* __restrict__ Wl,
    float* __restrict__ gsum)
{
    __shared__ float sWz0[1024], sWzo[1024], sWzi[1024];
    __shared__ float sWh0[1024], sWho[1024], sWhi[1024];
    __shared__ float sbz[32], sbh[32], swl[32];
    __shared__ float wsum[4];
    int tid = threadIdx.x;

    for (int idx = tid; idx < 1024; idx += 256) {
        int c = idx >> 5, f = idx & 31;
        int tr = f * 32 + c;
        // W[dir,k,c,f] flat = dir*4096 + k*2048 + c*32 + f ; only c<32 matters (H=0)
        sWz0[tr] = Wz[idx] + Wz[4096 + idx];
        sWzo[tr] = Wz[2048 + idx];
        sWzi[tr] = Wz[6144 + idx];
        sWh0[tr] = Wh[idx] + Wh[4096 + idx];
        sWho[tr] = Wh[2048 + idx];
        sWhi[tr] = Wh[6144 + idx];
    }
    if (tid < 32) {
        sbz[tid] = bz[tid];
        sbh[tid] = bh[tid];
        swl[tid] = Wl[tid];
    }
    __syncthreads();

    int i = blockIdx.x * 256 + tid;
    float s_acc = 0.f;
    if (i < NN) {
        float xv[F], tov[F], tiv[F];
        const float4* xr  = (const float4*)(x  + (size_t)i * F);
        const float4* tor = (const float4*)(To + (size_t)i * F);
        const float4* tir = (const float4*)(Ti + (size_t)i * F);
#pragma unroll
        for (int j = 0; j < 8; j++) {
            float4 p = xr[j];
            xv[4*j+0] = p.x; xv[4*j+1] = p.y; xv[4*j+2] = p.z; xv[4*j+3] = p.w;
            float4 a = tor[j];
            tov[4*j+0] = a.x; tov[4*j+1] = a.y; tov[4*j+2] = a.z; tov[4*j+3] = a.w;
            float4 b = tir[j];
            tiv[4*j+0] = b.x; tiv[4*j+1] = b.y; tiv[4*j+2] = b.z; tiv[4*j+3] = b.w;
        }
#pragma unroll 4
        for (int f = 0; f < 32; f++) {
            float gz = sbz[f], gh = sbh[f];
            const float* wz0 = &sWz0[f * 32];
            const float* wzo = &sWzo[f * 32];
            const float* wzi = &sWzi[f * 32];
            const float* wh0 = &sWh0[f * 32];
            const float* who = &sWho[f * 32];
            const float* whi = &sWhi[f * 32];
#pragma unroll
            for (int c = 0; c < 32; c++) {
                gz += xv[c] * wz0[c] + tov[c] * wzo[c] + tiv[c] * wzi[c];
                gh += xv[c] * wh0[c] + tov[c] * who[c] + tiv[c] * whi[c];
            }
            float Z  = 1.f / (1.f + __expf(-gz));
            float Ht = tanhf(gh);
            float hv = (1.f - Z) * Ht;
            hv = hv > 0.f ? hv : 0.f;
            s_acc += hv * swl[f];
        }
    }
#pragma unroll
    for (int off = 32; off > 0; off >>= 1) s_acc += __shfl_down(s_acc, off);
    if ((tid & 63) == 0) wsum[tid >> 6] = s_acc;
    __syncthreads();
    if (tid == 0) atomicAdd(gsum, wsum[0] + wsum[1] + wsum[2] + wsum[3]);
}

__global__ void k_final(const float* __restrict__ gsum,
                        const float* __restrict__ blin,
                        float* __restrict__ out) {
    out[0] = gsum[0] / (float)NN + blin[0];
}

extern "C" void kernel_launch(void* const* d_in, const int* in_sizes, int n_in,
                              void* d_out, int out_size, void* d_ws, size_t ws_size,
                              hipStream_t stream) {
    const float* x  = (const float*)d_in[0];
    const float* ew = (const float*)d_in[1];
    const float* Wz = (const float*)d_in[2];
    const float* bz = (const float*)d_in[3];
    // d_in[4], d_in[5] = W_r, b_r: dead (H=0 => H*R=0)
    const float* Wh = (const float*)d_in[6];
    const float* bh = (const float*)d_in[7];
    const float* Wl = (const float*)d_in[8];
    const float* bl = (const float*)d_in[9];
    const int* ei  = (const int*)d_in[10];
    const int* src = ei;
    const int* dst = ei + NE;

    // ws layout (4B words), total ~53.6 MB (proven footprint):
    // cur[2N*PS] | off[2N+1] | bsum[256] | bbase[256] | pool[2E int2] |
    // To[32N] | Ti[32N] | gsum
    int* iws   = (int*)d_ws;
    int* cur   = iws;
    int* off   = cur + (size_t)TWO_N * PS;
    int* bsum  = off + TWO_N + 1;
    int* bbase = bsum + 256;
    int2* pool = (int2*)(bbase + 256);
    float* To  = (float*)(pool + 2 * NE);
    float* Ti  = To + (size_t)NN * F;
    float* gsum = Ti + (size_t)NN * F;

    k_init <<<(TWO_N * PS + 255) / 256, 256, 0, stream>>>(cur, gsum);
    k_count<<<PART_GRID, 256, 0, stream>>>(src, dst, cur);
    k_scanb<<<SCAN_BLOCKS, 256, 0, stream>>>(cur, off, bsum);
    k_scant<<<1, 256, 0, stream>>>(bsum, bbase);
    k_scana<<<(TWO_N + 255) / 256, 256, 0, stream>>>(off, bbase, cur);
    k_fill <<<PART_GRID, 256, 0, stream>>>(src, dst, ew, cur, pool);
    k_gather<<<(NN + 7) / 8, 256, 0, stream>>>(x, off, pool, To, Ti);
    RecurrentGCN_69587060130083_kernel<<<(NN + 255) / 256, 256, 0, stream>>>(
        x, To, Ti, Wz, bz, Wh, bh, Wl, gsum);
    k_final<<<1, 1, 0, stream>>>(gsum, bl, (float*)d_out);
}